// Round 10
// baseline (283.901 us; speedup 1.0000x reference)
//
#include <hip/hip_runtime.h>
#include <hip/hip_bf16.h>

#define NPTS 12288
#define DD 128
#define CHUNKS 16
#define CHW (NPTS / CHUNKS)   // 768 cols per chunk
#define TILES (CHW / 64)      // 12 col-tiles of 64
#define NBG (NPTS / 128)      // 96 col-partial groups (128 rows each)

// descriptors pre-scaled by sqrt(10 * log2(e)) so MFMA result a = S*log2(e);
// then e^S = exp2(a) directly and argmax keys come from bits(exp2(a)).
#define PRESCALE 3.79828262f

typedef short bf16x8 __attribute__((ext_vector_type(8)));
typedef float f32x4 __attribute__((ext_vector_type(4)));

__device__ __forceinline__ float fast_exp2(float x) {
#if defined(__has_builtin)
#if __has_builtin(__builtin_amdgcn_exp2f)
  return __builtin_amdgcn_exp2f(x);
#else
  return exp2f(x);
#endif
#else
  return exp2f(x);
#endif
}

__device__ __forceinline__ short f2bf(float f) {  // RNE f32 -> bf16
  unsigned u = __float_as_uint(f);
  u += 0x7FFFu + ((u >> 16) & 1u);
  return (short)(u >> 16);
}

__device__ __forceinline__ unsigned umax(unsigned a, unsigned b) { return a > b ? a : b; }

// ---------------- pure conversion: f32 -> prescaled bf16 ----------------
__global__ void k_conv(const float* __restrict__ d0, const float* __restrict__ d1,
                       short* __restrict__ o0, short* __restrict__ o1) {
  unsigned t = blockIdx.x * 256u + threadIdx.x;
  const unsigned half = (NPTS * DD) / 4;
  const float* src; short* dst; unsigned g;
  if (t < half) { src = d0; dst = o0; g = t; }
  else          { src = d1; dst = o1; g = t - half; }
  float4 v = *(const float4*)(src + (size_t)g * 4);
  short4 r;
  r.x = f2bf(v.x * PRESCALE); r.y = f2bf(v.y * PRESCALE);
  r.z = f2bf(v.z * PRESCALE); r.w = f2bf(v.w * PRESCALE);
  *(short4*)(dst + (size_t)g * 4) = r;
}

// ---------------- main fused kernel ----------------
// R9 structure + 2-deep accumulator pipeline (T15, static accA/accB naming):
// section v: sync -> STAGE(v+1) -> MFMA(acc[v&1], tile v, buf[v&1])
//            -> EPILOGUE(acc[(v-1)&1], tile v-1) -> COMBINE(tile v-2).
// EPILOGUE(v-1) is data-independent of MFMA(v) => VALU overlaps MFMA/ds_read.
// crLds[v&1] written by EPI(v); COMBINE(v) reads it 1 sync later; next writer
// EPI(v+2) is 1 more sync away -> race-free. Tail peeled with extra syncs.
// Regs: accA+accB 64 + af 32 + state ~50 ~= 150 <= 170 budget of (256,3).
// DO NOT use (256,4): R8 proved catastrophic spill. (256,3) proven no-spill.
// C-frag: col = lane&15, row = (lane>>4)*4 + reg (m89/m91, verified R1-R9).
__launch_bounds__(256, 3)
__global__ void k_main(const short* __restrict__ d0b, const short* __restrict__ d1b,
                       uint2* __restrict__ colKV, uint2* __restrict__ rowKV) {
  __shared__ __align__(16) char bLds[2][16384];
  __shared__ uint2 crLds[2][4][64];
  const int widx = threadIdx.x >> 6;
  const int lane = threadIdx.x & 63;
  const int lo = lane & 15, hi = lane >> 4;
  const int chunk = blockIdx.x & (CHUNKS - 1);
  const int bg = blockIdx.x >> 4;                  // 0..95
  const int row0 = bg * 128 + widx * 32;
  const int cbase = chunk * CHW;

  const char* btile0 = (const char*)(d1b + (size_t)cbase * DD);  // tile t at +t*16384

  #define STAGE(tt, bb) do {                                                   \
    const char* gsrc_ = btile0 + (size_t)(tt) * 16384;                         \
    _Pragma("unroll")                                                          \
    for (int it_ = 0; it_ < 4; it_++) {                                        \
      int L_ = (widx << 12) + (it_ << 10) + (lane << 4);                       \
      int so_ = L_ ^ (((L_ >> 8) & 7) << 4);                                   \
      __builtin_amdgcn_global_load_lds((const void*)(gsrc_ + so_),             \
          (void*)(&bLds[bb][(widx << 12) + (it_ << 10)]), 16, 0, 0);           \
    }                                                                          \
  } while (0)

  // A fragments for this wave's 32 rows, all of K=128 (held whole kernel)
  bf16x8 af[2][4];
  #pragma unroll
  for (int i = 0; i < 2; i++)
    #pragma unroll
    for (int kk = 0; kk < 4; kk++)
      af[i][kk] = *(const bf16x8*)(d0b + (size_t)(row0 + i * 16 + lo) * DD + kk * 32 + hi * 8);

  float rowsum[2][4], rowkeyf[2][4];
  #pragma unroll
  for (int i = 0; i < 2; i++)
    #pragma unroll
    for (int r = 0; r < 4; r++) {
      rowsum[i][r] = 0.f;
      rowkeyf[i][r] = 0.f;
    }
  const unsigned rcbase = 0x3FFFu - (unsigned)(row0 + hi * 4);
  const int axor = (lo & 7) << 4;                  // lane-constant read swizzle

  f32x4 accA[2][4], accB[2][4];

  #define MFMA_STEP(ACC, CUR) do {                                             \
    _Pragma("unroll")                                                          \
    for (int i_ = 0; i_ < 2; i_++)                                             \
      _Pragma("unroll")                                                        \
      for (int j_ = 0; j_ < 4; j_++)                                           \
        ACC[i_][j_] = (f32x4){0.f, 0.f, 0.f, 0.f};                             \
    const char* bbuf_ = &bLds[CUR][0];                                         \
    _Pragma("unroll")                                                          \
    for (int kk_ = 0; kk_ < 4; kk_++) {                                        \
      bf16x8 bfr_[4];                                                          \
      _Pragma("unroll")                                                        \
      for (int j_ = 0; j_ < 4; j_++) {                                         \
        int bb_ = (((j_ << 4) + lo) << 8) + (kk_ << 6) + (hi << 4);            \
        bb_ ^= axor;                                                           \
        bfr_[j_] = *(const bf16x8*)(bbuf_ + bb_);                              \
      }                                                                        \
      _Pragma("unroll")                                                        \
      for (int j_ = 0; j_ < 4; j_++)                                           \
        _Pragma("unroll")                                                      \
        for (int i_ = 0; i_ < 2; i_++)                                         \
          ACC[i_][j_] = __builtin_amdgcn_mfma_f32_16x16x32_bf16(               \
              af[i_][kk_], bfr_[j_], ACC[i_][j_], 0, 0, 0);                    \
    }                                                                          \
  } while (0)

  #define EPI_STEP(ACC, TT) do {                                               \
    const int ct_ = cbase + (TT) * 64;                                         \
    _Pragma("unroll")                                                          \
    for (int j_ = 0; j_ < 4; j_++) {                                           \
      float colsum_ = 0.f, colkey_ = 0.f;                                      \
      const unsigned ccomp_ = 0x3FFFu - (unsigned)(ct_ + j_ * 16 + lo);        \
      _Pragma("unroll")                                                        \
      for (int i_ = 0; i_ < 2; i_++)                                           \
        _Pragma("unroll")                                                      \
        for (int r_ = 0; r_ < 4; r_++) {                                       \
          float e_ = fast_exp2(ACC[i_][j_][r_]);                               \
          unsigned tb_ = __float_as_uint(e_) & 0xFFFFC000u;                    \
          rowkeyf[i_][r_] = fmaxf(rowkeyf[i_][r_], __uint_as_float(tb_ | ccomp_)); \
          colkey_ = fmaxf(colkey_, __uint_as_float(tb_ | (rcbase - (unsigned)(i_ * 16 + r_)))); \
          rowsum[i_][r_] += e_;                                                \
          colsum_ += e_;                                                       \
        }                                                                      \
      colsum_ += __shfl_xor(colsum_, 16, 64);                                  \
      colsum_ += __shfl_xor(colsum_, 32, 64);                                  \
      colkey_ = fmaxf(colkey_, __shfl_xor(colkey_, 16, 64));                   \
      colkey_ = fmaxf(colkey_, __shfl_xor(colkey_, 32, 64));                   \
      if (hi == 0)                                                             \
        crLds[(TT) & 1][widx][j_ * 16 + lo] =                                  \
            make_uint2(__float_as_uint(colkey_), __float_as_uint(colsum_));    \
    }                                                                          \
  } while (0)

  #define COMBINE(TT) do {                                                     \
    if ((TT) >= 0 && lane < 16) {                                              \
      int c_ = widx * 16 + lane;                                               \
      const int p_ = (TT) & 1;                                                 \
      uint2 p0_ = crLds[p_][0][c_], p1_ = crLds[p_][1][c_];                    \
      uint2 p2_ = crLds[p_][2][c_], p3_ = crLds[p_][3][c_];                    \
      float s_ = __uint_as_float(p0_.y) + __uint_as_float(p1_.y) +             \
                 __uint_as_float(p2_.y) + __uint_as_float(p3_.y);              \
      float k_ = fmaxf(fmaxf(__uint_as_float(p0_.x), __uint_as_float(p1_.x)),  \
                       fmaxf(__uint_as_float(p2_.x), __uint_as_float(p3_.x))); \
      colKV[(size_t)bg * NPTS + cbase + (TT) * 64 + c_] =                      \
          make_uint2(__float_as_uint(k_), __float_as_uint(s_));                \
    }                                                                          \
  } while (0)

  // prologue: tile 0 staged+computed, tile 1 in flight
  STAGE(0, 0);
  __syncthreads();
  STAGE(1, 1);
  MFMA_STEP(accA, 0);                 // tile 0 -> accA

  #pragma unroll 1
  for (int k = 0; k < 5; k++) {
    const int o = 2 * k + 1;
    // section v = o (odd): MFMA accB, EPI accA
    __syncthreads();                  // buf1 = tile o ready
    STAGE(o + 1, 0);                  // tile o+1 (even) -> buf0
    MFMA_STEP(accB, 1);               // tile o
    EPI_STEP(accA, o - 1);            // tile o-1 -> crLds[0]
    COMBINE(2 * k - 1);               // tile 2k-1 <- crLds[1]
    // section v = o+1 (even): MFMA accA, EPI accB
    __syncthreads();                  // buf0 = tile o+1 ready
    if (o + 2 < TILES) STAGE(o + 2, 1);  // tile o+2 (odd) -> buf1
    MFMA_STEP(accA, 0);               // tile o+1
    EPI_STEP(accB, o);                // tile o -> crLds[1]
    COMBINE(2 * k);                   // tile 2k <- crLds[0]
  }

  // section v = 11
  __syncthreads();                    // buf1 = tile 11 ready
  MFMA_STEP(accB, 1);                 // tile 11
  EPI_STEP(accA, 10);                 // tile 10 -> crLds[0]
  COMBINE(9);                         // tile 9 <- crLds[1]
  __syncthreads();                    // combine(9) done before crLds[1] rewrite
  EPI_STEP(accB, 11);                 // tile 11 -> crLds[1]
  __syncthreads();
  COMBINE(10);                        // <- crLds[0]
  COMBINE(11);                        // <- crLds[1]

  // row partials: reduce over lo bits (cols), lanes with lo==0 write
  #pragma unroll
  for (int i = 0; i < 2; i++)
    #pragma unroll
    for (int r = 0; r < 4; r++) {
      float s = rowsum[i][r];
      float k = rowkeyf[i][r];
      s += __shfl_xor(s, 1, 64); s += __shfl_xor(s, 2, 64);
      s += __shfl_xor(s, 4, 64); s += __shfl_xor(s, 8, 64);
      k = fmaxf(k, __shfl_xor(k, 1, 64));
      k = fmaxf(k, __shfl_xor(k, 2, 64));
      k = fmaxf(k, __shfl_xor(k, 4, 64));
      k = fmaxf(k, __shfl_xor(k, 8, 64));
      if (lo == 0) {
        int row = row0 + i * 16 + hi * 4 + r;
        rowKV[(size_t)chunk * NPTS + row] = make_uint2(__float_as_uint(k), __float_as_uint(s));
      }
    }
  #undef STAGE
  #undef MFMA_STEP
  #undef EPI_STEP
  #undef COMBINE
}

// ---------------- fused reduce (+ exact positive dots): blocks 0..47 cols, 48..95 rows ----
__global__ void k_red(const uint2* __restrict__ colKV, const uint2* __restrict__ rowKV,
                      const float* __restrict__ d0, const float* __restrict__ d1,
                      const int* __restrict__ c0, const int* __restrict__ c1,
                      unsigned* __restrict__ best0, unsigned* __restrict__ best1,
                      float* __restrict__ l0part, float* __restrict__ l1part) {
  float v;
  if (blockIdx.x < 48) {
    int m = blockIdx.x * 256 + threadIdx.x;
    float s = 0.f; unsigned k = 0u;
    #pragma unroll 8
    for (int b = 0; b < NBG; b++) {
      uint2 kv = colKV[(size_t)b * NPTS + m];
      s += __uint_as_float(kv.y);
      k = umax(k, kv.x);
    }
    best1[m] = 0x3FFFu - (k & 0x3FFFu);
    int cc = c1[m];
    int i = cc > 0 ? cc : 0;
    const float4* pa = (const float4*)(d0 + (size_t)i * DD);
    const float4* pb = (const float4*)(d1 + (size_t)m * DD);
    float dot = 0.f;
    #pragma unroll 8
    for (int q = 0; q < DD / 4; q++) {
      float4 a = pa[q], b = pb[q];
      dot += a.x * b.x + a.y * b.y + a.z * b.z + a.w * b.w;
    }
    v = (cc >= 0) ? (logf(s) - 10.0f * dot) : 0.f;
  } else {
    int n = (blockIdx.x - 48) * 256 + threadIdx.x;
    float s = 0.f; unsigned k = 0u;
    #pragma unroll
    for (int c = 0; c < CHUNKS; c++) {
      uint2 kv = rowKV[(size_t)c * NPTS + n];
      s += __uint_as_float(kv.y);
      k = umax(k, kv.x);
    }
    best0[n] = 0x3FFFu - (k & 0x3FFFu);
    int cc = c0[n];
    int i = cc > 0 ? cc : 0;
    const float4* pa = (const float4*)(d0 + (size_t)n * DD);
    const float4* pb = (const float4*)(d1 + (size_t)i * DD);
    float dot = 0.f;
    #pragma unroll 8
    for (int q = 0; q < DD / 4; q++) {
      float4 a = pa[q], b = pb[q];
      dot += a.x * b.x + a.y * b.y + a.z * b.z + a.w * b.w;
    }
    v = (cc >= 0) ? (logf(s) - 10.0f * dot) : 0.f;
  }
  __shared__ float red[256];
  red[threadIdx.x] = v; __syncthreads();
  for (int st = 128; st > 0; st >>= 1) {
    if (threadIdx.x < st) red[threadIdx.x] += red[threadIdx.x + st];
    __syncthreads();
  }
  if (threadIdx.x == 0) {
    if (blockIdx.x < 48) l1part[blockIdx.x] = red[0];
    else                 l0part[blockIdx.x - 48] = red[0];
  }
}

// ---------------- stats partials: mutual-NN precision/recall counts (48 blocks) ----------
__global__ void k_stats(const int* __restrict__ c0, const int* __restrict__ c1,
                        const float* __restrict__ lg0, const float* __restrict__ lg1,
                        const unsigned* __restrict__ best0, const unsigned* __restrict__ best1,
                        int4* __restrict__ statpart) {
  int n = blockIdx.x * 256 + threadIdx.x;
  int cc = c0[n];
  bool m0 = cc >= 0;
  int b0 = (int)best0[n];
  bool mutual = ((int)best1[b0] == n);
  bool pred = mutual && (lg0[n] >= 0.f) && (lg1[b0] >= 0.f);
  int4 v;
  v.x = m0 ? 1 : 0;                               // m0 count
  v.y = (c1[n] >= 0) ? 1 : 0;                     // m1 count
  v.z = (pred && m0 && b0 == cc) ? 1 : 0;         // tp
  v.w = pred ? 1 : 0;                             // predicted
  __shared__ int4 red[256];
  red[threadIdx.x] = v; __syncthreads();
  for (int st = 128; st > 0; st >>= 1) {
    if (threadIdx.x < st) {
      int4 o = red[threadIdx.x + st];
      red[threadIdx.x].x += o.x; red[threadIdx.x].y += o.y;
      red[threadIdx.x].z += o.z; red[threadIdx.x].w += o.w;
    }
    __syncthreads();
  }
  if (threadIdx.x == 0) statpart[blockIdx.x] = red[0];
}

// ---------------- final: combine 48 partials of everything ----------------
__global__ void k_final(const float* __restrict__ l0part, const float* __restrict__ l1part,
                        const int4* __restrict__ statpart, float* __restrict__ out) {
  const int tid = threadIdx.x;   // 64 threads
  float l0s = 0.f, l1s = 0.f;
  int4 st = make_int4(0, 0, 0, 0);
  if (tid < 48) {
    l0s = l0part[tid]; l1s = l1part[tid];
    st = statpart[tid];
  }
  #pragma unroll
  for (int off = 32; off >= 1; off >>= 1) {
    l0s += __shfl_down(l0s, off, 64);
    l1s += __shfl_down(l1s, off, 64);
    st.x += __shfl_down(st.x, off, 64);
    st.y += __shfl_down(st.y, off, 64);
    st.z += __shfl_down(st.z, off, 64);
    st.w += __shfl_down(st.w, off, 64);
  }
  if (tid == 0) {
    int M0 = st.x > 0 ? st.x : 1;
    int M1 = st.y > 0 ? st.y : 1;
    int PR = st.w > 0 ? st.w : 1;
    out[0] = l0s / (float)M0;
    out[1] = l1s / (float)M1;
    out[2] = (float)st.z / (float)PR;
    out[3] = (float)st.z / (float)M0;
  }
}

extern "C" void kernel_launch(void* const* d_in, const int* in_sizes, int n_in,
                              void* d_out, int out_size, void* d_ws, size_t ws_size,
                              hipStream_t stream) {
  const float* desc0 = (const float*)d_in[0];
  const float* desc1 = (const float*)d_in[1];
  const int* corr0   = (const int*)d_in[2];
  const int* corr1   = (const int*)d_in[3];
  const float* lg0   = (const float*)d_in[4];
  const float* lg1   = (const float*)d_in[5];
  float* out = (float*)d_out;

  char* w = (char*)d_ws;
  short* d0b   = (short*)(w);                   // 3,145,728 B
  short* d1b   = (short*)(w + 3145728);         // 3,145,728 B
  uint2* colKV = (uint2*)(w + 6291456);         //  9,437,184 B  [96][12288]
  uint2* rowKV = (uint2*)(w + 15728640);        //  1,572,864 B  [16][12288]
  unsigned* best0 = (unsigned*)(w + 17301504);  //     49,152 B
  unsigned* best1 = (unsigned*)(w + 17350656);  //     49,152 B
  float* l0part = (float*)(w + 17399808);       //        192 B
  float* l1part = (float*)(w + 17400000);       //        192 B
  int4* statpart = (int4*)(w + 17400192);       //        768 B

  k_conv<<<3072, 256, 0, stream>>>(desc0, desc1, d0b, d1b);
  k_main<<<1536, 256, 0, stream>>>(d0b, d1b, colKV, rowKV);
  k_red<<<96, 256, 0, stream>>>(colKV, rowKV, desc0, desc1, corr0, corr1, best0, best1, l0part, l1part);
  k_stats<<<48, 256, 0, stream>>>(corr0, corr1, lg0, lg1, best0, best1, statpart);
  k_final<<<1, 64, 0, stream>>>(l0part, l1part, statpart, out);
}

// Round 11
// 107.488 us; speedup vs baseline: 2.6412x; 2.6412x over previous
//
#include <hip/hip_runtime.h>
#include <hip/hip_bf16.h>

#define NPTS 12288
#define DD 128
#define CHUNKS 16
#define CHW (NPTS / CHUNKS)   // 768 cols per chunk
#define TILES (CHW / 64)      // 12 col-tiles of 64
#define NBG (NPTS / 128)      // 96 col-partial groups (128 rows each)

// descriptors pre-scaled by sqrt(10 * log2(e)) so MFMA result a = S*log2(e);
// then e^S = exp2(a) directly and argmax keys come from bits(exp2(a)).
#define PRESCALE 3.79828262f

typedef short bf16x8 __attribute__((ext_vector_type(8)));
typedef float f32x4 __attribute__((ext_vector_type(4)));

__device__ __forceinline__ float fast_exp2(float x) {
#if defined(__has_builtin)
#if __has_builtin(__builtin_amdgcn_exp2f)
  return __builtin_amdgcn_exp2f(x);
#else
  return exp2f(x);
#endif
#else
  return exp2f(x);
#endif
}

__device__ __forceinline__ short f2bf(float f) {  // RNE f32 -> bf16
  unsigned u = __float_as_uint(f);
  u += 0x7FFFu + ((u >> 16) & 1u);
  return (short)(u >> 16);
}

__device__ __forceinline__ unsigned umax(unsigned a, unsigned b) { return a > b ? a : b; }

// ---------------- pure conversion: f32 -> prescaled bf16 (image-1 only) ----------------
__global__ void k_conv(const float* __restrict__ d1, short* __restrict__ o1) {
  unsigned g = blockIdx.x * 256u + threadIdx.x;    // 1536 blocks x 256 = NPTS*DD/4
  float4 v = *(const float4*)(d1 + (size_t)g * 4);
  short4 r;
  r.x = f2bf(v.x * PRESCALE); r.y = f2bf(v.y * PRESCALE);
  r.z = f2bf(v.z * PRESCALE); r.w = f2bf(v.w * PRESCALE);
  *(short4*)(o1 + (size_t)g * 4) = r;
}

// ---------------- main fused kernel ----------------
// R9 structure (proven 86us, 84 VGPR + 32 AGPR, zero spill) with:
//  - full 16-slot LDS swizzle: byte ^= ((row&15)<<4); read term lo<<4 is
//    lane-constant (row = j*16+lo => row&15 = lo). 16 lanes -> 16 distinct
//    16B slots -> 2-way bank aliasing only (free per m136). R9's (row&7)
//    swizzle left a measured 4-way conflict (4 extra cyc/ds_read_b128).
//  - A fragments converted in-register from f32 desc0 (once per kernel);
//    k_conv now converts only desc1.
// DO NOT: (256,4) [R8: spill], 2-deep acc pipeline [R10: spill],
// A in LDS [R5: serial ds_reads]. (256,3) single-acc is the stable optimum.
// C-frag: col = lane&15, row = (lane>>4)*4 + reg (m89/m91, verified R1-R10).
__launch_bounds__(256, 3)
__global__ void k_main(const float* __restrict__ desc0, const short* __restrict__ d1b,
                       uint2* __restrict__ colKV, uint2* __restrict__ rowKV) {
  __shared__ __align__(16) char bLds[2][16384];
  __shared__ uint2 crLds[2][4][64];
  const int widx = threadIdx.x >> 6;
  const int lane = threadIdx.x & 63;
  const int lo = lane & 15, hi = lane >> 4;
  const int chunk = blockIdx.x & (CHUNKS - 1);
  const int bg = blockIdx.x >> 4;                  // 0..95
  const int row0 = bg * 128 + widx * 32;
  const int cbase = chunk * CHW;

  const char* btile0 = (const char*)(d1b + (size_t)cbase * DD);  // tile t at +t*16384

  // stage helper: wave w writes LDS [w*4096, +4096) linearly in 4 rounds;
  // global source pre-swizzled so lds[linear] = tile[linear ^ ((row&15)<<4)].
  #define STAGE(tt, bb) do {                                                   \
    const char* gsrc_ = btile0 + (size_t)(tt) * 16384;                         \
    _Pragma("unroll")                                                          \
    for (int it_ = 0; it_ < 4; it_++) {                                        \
      int L_ = (widx << 12) + (it_ << 10) + (lane << 4);                       \
      int so_ = L_ ^ (((L_ >> 8) & 15) << 4);                                  \
      __builtin_amdgcn_global_load_lds((const void*)(gsrc_ + so_),             \
          (void*)(&bLds[bb][(widx << 12) + (it_ << 10)]), 16, 0, 0);           \
    }                                                                          \
  } while (0)

  // A fragments for this wave's 32 rows, all of K=128: convert from f32
  // in-register (once per kernel; 16 float4 loads + 64 cvt, negligible)
  bf16x8 af[2][4];
  #pragma unroll
  for (int i = 0; i < 2; i++)
    #pragma unroll
    for (int kk = 0; kk < 4; kk++) {
      const float* ap = desc0 + (size_t)(row0 + i * 16 + lo) * DD + kk * 32 + hi * 8;
      float4 x = *(const float4*)ap;
      float4 y = *(const float4*)(ap + 4);
      bf16x8 f;
      f[0] = f2bf(x.x * PRESCALE); f[1] = f2bf(x.y * PRESCALE);
      f[2] = f2bf(x.z * PRESCALE); f[3] = f2bf(x.w * PRESCALE);
      f[4] = f2bf(y.x * PRESCALE); f[5] = f2bf(y.y * PRESCALE);
      f[6] = f2bf(y.z * PRESCALE); f[7] = f2bf(y.w * PRESCALE);
      af[i][kk] = f;
    }

  float rowsum[2][4], rowkeyf[2][4];
  #pragma unroll
  for (int i = 0; i < 2; i++)
    #pragma unroll
    for (int r = 0; r < 4; r++) {
      rowsum[i][r] = 0.f;
      rowkeyf[i][r] = 0.f;
    }
  const unsigned rcbase = 0x3FFFu - (unsigned)(row0 + hi * 4);
  const int axor = lo << 4;                        // lane-constant read swizzle (row&15 = lo)

  STAGE(0, 0);
  __syncthreads();   // vmcnt(0) drain: tile 0 resident

  #pragma unroll 1
  for (int t = 0; t < TILES; t++) {
    const int cur = t & 1;
    if (t + 1 < TILES) STAGE(t + 1, cur ^ 1);

    f32x4 acc[2][4];
    #pragma unroll
    for (int i = 0; i < 2; i++)
      #pragma unroll
      for (int j = 0; j < 4; j++)
        acc[i][j] = (f32x4){0.f, 0.f, 0.f, 0.f};

    const char* bbuf = &bLds[cur][0];
    #pragma unroll
    for (int kk = 0; kk < 4; kk++) {
      bf16x8 bfr[4];
      #pragma unroll
      for (int j = 0; j < 4; j++) {
        int bbyte = (((j << 4) + lo) << 8) + (kk << 6) + (hi << 4);
        bbyte ^= axor;
        bfr[j] = *(const bf16x8*)(bbuf + bbyte);
      }
      #pragma unroll
      for (int j = 0; j < 4; j++)
        #pragma unroll
        for (int i = 0; i < 2; i++)
          acc[i][j] = __builtin_amdgcn_mfma_f32_16x16x32_bf16(af[i][kk], bfr[j], acc[i][j], 0, 0, 0);
    }

    // fused epilogue: e = e^S = exp2(a); float-typed keys (max3-fusable)
    const int ct = cbase + t * 64;
    #pragma unroll
    for (int j = 0; j < 4; j++) {
      float colsum = 0.f;
      float colkeyf = 0.f;
      const unsigned ccomp = 0x3FFFu - (unsigned)(ct + j * 16 + lo);
      #pragma unroll
      for (int i = 0; i < 2; i++)
        #pragma unroll
        for (int r = 0; r < 4; r++) {
          float e = fast_exp2(acc[i][j][r]);
          unsigned tb = __float_as_uint(e) & 0xFFFFC000u;
          rowkeyf[i][r] = fmaxf(rowkeyf[i][r], __uint_as_float(tb | ccomp));
          colkeyf = fmaxf(colkeyf, __uint_as_float(tb | (rcbase - (unsigned)(i * 16 + r))));
          rowsum[i][r] += e;
          colsum += e;
        }
      colsum += __shfl_xor(colsum, 16, 64);
      colsum += __shfl_xor(colsum, 32, 64);
      colkeyf = fmaxf(colkeyf, __shfl_xor(colkeyf, 16, 64));
      colkeyf = fmaxf(colkeyf, __shfl_xor(colkeyf, 32, 64));
      if (hi == 0)
        crLds[cur][widx][j * 16 + lo] = make_uint2(__float_as_uint(colkeyf), __float_as_uint(colsum));
    }

    __syncthreads();   // crLds visible; bLds[cur^1] staged; all done with buf[cur]

    // combine 4 waves' col partials; wave w handles its own 16 columns
    if (lane < 16) {
      int c = widx * 16 + lane;
      uint2 p0 = crLds[cur][0][c], p1 = crLds[cur][1][c];
      uint2 p2 = crLds[cur][2][c], p3 = crLds[cur][3][c];
      float s = __uint_as_float(p0.y) + __uint_as_float(p1.y) +
                __uint_as_float(p2.y) + __uint_as_float(p3.y);
      float k = fmaxf(fmaxf(__uint_as_float(p0.x), __uint_as_float(p1.x)),
                      fmaxf(__uint_as_float(p2.x), __uint_as_float(p3.x)));
      colKV[(size_t)bg * NPTS + ct + c] = make_uint2(__float_as_uint(k), __float_as_uint(s));
    }
  }

  // row partials: reduce over lo bits (cols), lanes with lo==0 write
  #pragma unroll
  for (int i = 0; i < 2; i++)
    #pragma unroll
    for (int r = 0; r < 4; r++) {
      float s = rowsum[i][r];
      float k = rowkeyf[i][r];
      s += __shfl_xor(s, 1, 64); s += __shfl_xor(s, 2, 64);
      s += __shfl_xor(s, 4, 64); s += __shfl_xor(s, 8, 64);
      k = fmaxf(k, __shfl_xor(k, 1, 64));
      k = fmaxf(k, __shfl_xor(k, 2, 64));
      k = fmaxf(k, __shfl_xor(k, 4, 64));
      k = fmaxf(k, __shfl_xor(k, 8, 64));
      if (lo == 0) {
        int row = row0 + i * 16 + hi * 4 + r;
        rowKV[(size_t)chunk * NPTS + row] = make_uint2(__float_as_uint(k), __float_as_uint(s));
      }
    }
  #undef STAGE
}

// ---------------- fused reduce (+ exact positive dots): blocks 0..47 cols, 48..95 rows ----
__global__ void k_red(const uint2* __restrict__ colKV, const uint2* __restrict__ rowKV,
                      const float* __restrict__ d0, const float* __restrict__ d1,
                      const int* __restrict__ c0, const int* __restrict__ c1,
                      unsigned* __restrict__ best0, unsigned* __restrict__ best1,
                      float* __restrict__ l0part, float* __restrict__ l1part) {
  float v;
  if (blockIdx.x < 48) {
    int m = blockIdx.x * 256 + threadIdx.x;
    float s = 0.f; unsigned k = 0u;
    #pragma unroll 8
    for (int b = 0; b < NBG; b++) {
      uint2 kv = colKV[(size_t)b * NPTS + m];
      s += __uint_as_float(kv.y);
      k = umax(k, kv.x);
    }
    best1[m] = 0x3FFFu - (k & 0x3FFFu);
    int cc = c1[m];
    int i = cc > 0 ? cc : 0;
    const float4* pa = (const float4*)(d0 + (size_t)i * DD);
    const float4* pb = (const float4*)(d1 + (size_t)m * DD);
    float dot = 0.f;
    #pragma unroll 8
    for (int q = 0; q < DD / 4; q++) {
      float4 a = pa[q], b = pb[q];
      dot += a.x * b.x + a.y * b.y + a.z * b.z + a.w * b.w;
    }
    v = (cc >= 0) ? (logf(s) - 10.0f * dot) : 0.f;
  } else {
    int n = (blockIdx.x - 48) * 256 + threadIdx.x;
    float s = 0.f; unsigned k = 0u;
    #pragma unroll
    for (int c = 0; c < CHUNKS; c++) {
      uint2 kv = rowKV[(size_t)c * NPTS + n];
      s += __uint_as_float(kv.y);
      k = umax(k, kv.x);
    }
    best0[n] = 0x3FFFu - (k & 0x3FFFu);
    int cc = c0[n];
    int i = cc > 0 ? cc : 0;
    const float4* pa = (const float4*)(d0 + (size_t)n * DD);
    const float4* pb = (const float4*)(d1 + (size_t)i * DD);
    float dot = 0.f;
    #pragma unroll 8
    for (int q = 0; q < DD / 4; q++) {
      float4 a = pa[q], b = pb[q];
      dot += a.x * b.x + a.y * b.y + a.z * b.z + a.w * b.w;
    }
    v = (cc >= 0) ? (logf(s) - 10.0f * dot) : 0.f;
  }
  __shared__ float red[256];
  red[threadIdx.x] = v; __syncthreads();
  for (int st = 128; st > 0; st >>= 1) {
    if (threadIdx.x < st) red[threadIdx.x] += red[threadIdx.x + st];
    __syncthreads();
  }
  if (threadIdx.x == 0) {
    if (blockIdx.x < 48) l1part[blockIdx.x] = red[0];
    else                 l0part[blockIdx.x - 48] = red[0];
  }
}

// ---------------- stats partials: mutual-NN precision/recall counts (48 blocks) ----------
__global__ void k_stats(const int* __restrict__ c0, const int* __restrict__ c1,
                        const float* __restrict__ lg0, const float* __restrict__ lg1,
                        const unsigned* __restrict__ best0, const unsigned* __restrict__ best1,
                        int4* __restrict__ statpart) {
  int n = blockIdx.x * 256 + threadIdx.x;
  int cc = c0[n];
  bool m0 = cc >= 0;
  int b0 = (int)best0[n];
  bool mutual = ((int)best1[b0] == n);
  bool pred = mutual && (lg0[n] >= 0.f) && (lg1[b0] >= 0.f);
  int4 v;
  v.x = m0 ? 1 : 0;                               // m0 count
  v.y = (c1[n] >= 0) ? 1 : 0;                     // m1 count
  v.z = (pred && m0 && b0 == cc) ? 1 : 0;         // tp
  v.w = pred ? 1 : 0;                             // predicted
  __shared__ int4 red[256];
  red[threadIdx.x] = v; __syncthreads();
  for (int st = 128; st > 0; st >>= 1) {
    if (threadIdx.x < st) {
      int4 o = red[threadIdx.x + st];
      red[threadIdx.x].x += o.x; red[threadIdx.x].y += o.y;
      red[threadIdx.x].z += o.z; red[threadIdx.x].w += o.w;
    }
    __syncthreads();
  }
  if (threadIdx.x == 0) statpart[blockIdx.x] = red[0];
}

// ---------------- final: combine 48 partials of everything ----------------
__global__ void k_final(const float* __restrict__ l0part, const float* __restrict__ l1part,
                        const int4* __restrict__ statpart, float* __restrict__ out) {
  const int tid = threadIdx.x;   // 64 threads
  float l0s = 0.f, l1s = 0.f;
  int4 st = make_int4(0, 0, 0, 0);
  if (tid < 48) {
    l0s = l0part[tid]; l1s = l1part[tid];
    st = statpart[tid];
  }
  #pragma unroll
  for (int off = 32; off >= 1; off >>= 1) {
    l0s += __shfl_down(l0s, off, 64);
    l1s += __shfl_down(l1s, off, 64);
    st.x += __shfl_down(st.x, off, 64);
    st.y += __shfl_down(st.y, off, 64);
    st.z += __shfl_down(st.z, off, 64);
    st.w += __shfl_down(st.w, off, 64);
  }
  if (tid == 0) {
    int M0 = st.x > 0 ? st.x : 1;
    int M1 = st.y > 0 ? st.y : 1;
    int PR = st.w > 0 ? st.w : 1;
    out[0] = l0s / (float)M0;
    out[1] = l1s / (float)M1;
    out[2] = (float)st.z / (float)PR;
    out[3] = (float)st.z / (float)M0;
  }
}

extern "C" void kernel_launch(void* const* d_in, const int* in_sizes, int n_in,
                              void* d_out, int out_size, void* d_ws, size_t ws_size,
                              hipStream_t stream) {
  const float* desc0 = (const float*)d_in[0];
  const float* desc1 = (const float*)d_in[1];
  const int* corr0   = (const int*)d_in[2];
  const int* corr1   = (const int*)d_in[3];
  const float* lg0   = (const float*)d_in[4];
  const float* lg1   = (const float*)d_in[5];
  float* out = (float*)d_out;

  char* w = (char*)d_ws;
  short* d1b   = (short*)(w);                   //  3,145,728 B
  uint2* colKV = (uint2*)(w + 3145728);         //  9,437,184 B  [96][12288]
  uint2* rowKV = (uint2*)(w + 12582912);        //  1,572,864 B  [16][12288]
  unsigned* best0 = (unsigned*)(w + 14155776);  //     49,152 B
  unsigned* best1 = (unsigned*)(w + 14204928);  //     49,152 B
  float* l0part = (float*)(w + 14254080);       //        192 B
  float* l1part = (float*)(w + 14254272);       //        192 B
  int4* statpart = (int4*)(w + 14254464);       //        768 B

  k_conv<<<1536, 256, 0, stream>>>(desc1, d1b);
  k_main<<<1536, 256, 0, stream>>>(desc0, d1b, colKV, rowKV);
  k_red<<<96, 256, 0, stream>>>(colKV, rowKV, desc0, desc1, corr0, corr1, best0, best1, l0part, l1part);
  k_stats<<<48, 256, 0, stream>>>(corr0, corr1, lg0, lg1, best0, best1, statpart);
  k_final<<<1, 64, 0, stream>>>(l0part, l1part, statpart, out);
}